// Round 4
// baseline (369.771 us; speedup 1.0000x reference)
//
#include <hip/hip_runtime.h>

// B=2, S=2048, E=1024, H=16. Output tuple: out [B,S,E] (4,194,304 f32) +
// attn [B,H,S,S] (134,217,728 f32, constant 1/2048). 553.6 MB writes -> the
// roofline is HBM write BW (~6.8 TB/s achievable => ~88 us floor incl reads).
//
// Depth-2 plan:
//  K1: colsum partials of value  ||  Wc = Wv@Wo (+bias row bc = bv@Wo+bo)
//      ||  fill attn chunk A          (Wc has no deps on the chain)
//  K2: vbar = reduce(part1)/S -> outrow = vbar@Wc + bc -> broadcast to out
//      ||  fill attn chunk B
// Fallback (small ws): proven R3 4-kernel pipeline.

typedef float floatx4 __attribute__((ext_vector_type(4)));

#define ATTN_BASE4 1048576LL    // B*S*E/4
#define TOT4       34603008LL
#define K1_FILLB   3840
#define K1_FILL4   15728640LL   // K1_FILLB*4096
#define K2_FILLB   4352

__device__ __forceinline__ void fill_at(float* __restrict__ out, long long f4base) {
    floatx4* o4 = (floatx4*)out;
    const floatx4 av = (floatx4)(1.0f / 2048.0f);   // exact softmax of const scores
    long long base = f4base + threadIdx.x;
    #pragma unroll
    for (int it = 0; it < 16; ++it)
        __builtin_nontemporal_store(av, &o4[base + it * 256]);
}

// ---------------------------------------------------------------------------
// K1: blocks 0..255 colsum | 256..527 GEMM Wc (17x16 tiles of 64x64, row 16 =
// bias row) | rest fill chunk A.
__global__ void __launch_bounds__(256)
k1_colsum_gemm_fill(const float* __restrict__ value,
                    const float* __restrict__ Wv, const float* __restrict__ bv,
                    const float* __restrict__ Wo, const float* __restrict__ bo,
                    float* __restrict__ part1, float* __restrict__ wc,
                    float* __restrict__ out) {
    int blk = blockIdx.x, t = threadIdx.x;
    if (blk < 256) {
        int b = blk >> 7, sp = blk & 127;
        const floatx4* v4 = (const floatx4*)value;
        floatx4 acc = (floatx4)0.0f;
        int rowbase = b * 2048 + sp * 16;
        #pragma unroll
        for (int r = 0; r < 16; ++r)
            acc += v4[(size_t)(rowbase + r) * 256 + t];
        ((floatx4*)part1)[(size_t)(b * 128 + sp) * 256 + t] = acc;
    } else if (blk < 528) {
        int g = blk - 256;
        int kt = g >> 4, et = g & 15;          // k-tile 0..16, e-tile 0..15
        int k_local = t >> 2, eq = t & 3;      // 64 k-rows x 4 e-quads
        int e0 = et * 64 + eq * 16;            // 16 outputs (4 float4)
        const float* arow;
        bool active = true;
        if (kt < 16) arow = Wv + (size_t)(kt * 64 + k_local) * 1024;
        else { active = (k_local == 0); arow = bv; }
        if (active) {
            const floatx4* W4 = (const floatx4*)Wo;
            floatx4 a0 = (floatx4)0.f, a1 = (floatx4)0.f,
                    a2 = (floatx4)0.f, a3 = (floatx4)0.f;
            int c4 = e0 >> 2;
            #pragma unroll 4
            for (int j = 0; j < 1024; ++j) {
                float s = arow[j];
                const floatx4* wr = W4 + (size_t)j * 256 + c4;
                a0 += s * wr[0]; a1 += s * wr[1];
                a2 += s * wr[2]; a3 += s * wr[3];
            }
            floatx4* dst;
            if (kt < 16) {
                dst = (floatx4*)(wc + (size_t)(kt * 64 + k_local) * 1024 + e0);
            } else {
                const floatx4* b4 = (const floatx4*)bo;
                a0 += b4[c4]; a1 += b4[c4 + 1]; a2 += b4[c4 + 2]; a3 += b4[c4 + 3];
                dst = (floatx4*)(wc + (size_t)1024 * 1024 + e0);
            }
            dst[0] = a0; dst[1] = a1; dst[2] = a2; dst[3] = a3;
        }
    } else {
        fill_at(out, ATTN_BASE4 + (long long)(blk - 528) * 4096);
    }
}

// ---------------------------------------------------------------------------
// K2: blocks 0..63 -> (b, 32-col slice): redundant vbar reduce (L2-resident
// part1), matvec with Wc slice + bias row, broadcast 32 cols to 2048 rows.
// rest -> fill chunk B.
__global__ void __launch_bounds__(256)
k2_outrow_bcast_fill(const float* __restrict__ part1,
                     const float* __restrict__ wc,
                     float* __restrict__ out) {
    int blk = blockIdx.x, t = threadIdx.x;
    if (blk < 64) {
        __shared__ __align__(16) float vbar[1024];
        __shared__ float red[256];
        __shared__ __align__(16) float orow[32];
        int b = blk >> 5, es = blk & 31;
        int e0 = es * 32;
        // vbar[b][:] = mean_s value  (reduce 128 partials, fixed order)
        const floatx4* p4 = (const floatx4*)part1 + (size_t)b * 128 * 256;
        floatx4 acc = (floatx4)0.0f;
        for (int sp = 0; sp < 128; ++sp)
            acc += p4[sp * 256 + t];
        ((floatx4*)vbar)[t] = acc * (1.0f / 2048.0f);
        __syncthreads();
        // outrow slice = vbar @ Wc[:, e0:e0+32] (8 k-segments x 32 cols)
        int es_l = t & 31, seg = t >> 5;
        const float* wcol = wc + e0 + es_l;
        float part = 0.f;
        int kbase = seg * 128;
        #pragma unroll 8
        for (int kk = 0; kk < 128; ++kk) {
            int k = kbase + kk;
            part += vbar[k] * wcol[(size_t)k * 1024];
        }
        red[t] = part;
        __syncthreads();
        if (t < 32) {
            float o = wc[(size_t)1024 * 1024 + e0 + t];   // bc row
            #pragma unroll
            for (int g = 0; g < 8; ++g) o += red[g * 32 + t];
            orow[t] = o;
        }
        __syncthreads();
        // broadcast 8 float4 cols to 2048 rows: lanes = 8 f4 x 8 rows
        floatx4 w = ((const floatx4*)orow)[t & 7];
        int rg = t >> 3;                                  // 0..31
        floatx4* o4 = (floatx4*)out;
        size_t colbase = (size_t)es * 8 + (t & 7);
        size_t rowstart = (size_t)b * 2048 + (size_t)rg * 64;
        #pragma unroll 8
        for (int i = 0; i < 64; ++i)
            __builtin_nontemporal_store(w, &o4[(rowstart + i) * 256 + colbase]);
    } else {
        fill_at(out, ATTN_BASE4 + K1_FILL4 + (long long)(blk - 64) * 4096);
    }
}

// ======================= fallback path (small ws) ==========================
__global__ void fb_colsum_fill(const float* __restrict__ value,
                               float* __restrict__ part1, float* __restrict__ out) {
    int blk = blockIdx.x;
    if (blk < 256) {
        int b = blk >> 7, sp = blk & 127, tid = threadIdx.x;
        const floatx4* v4 = (const floatx4*)value;
        floatx4 acc = (floatx4)0.0f;
        int rowbase = b * 2048 + sp * 16;
        #pragma unroll
        for (int r = 0; r < 16; ++r)
            acc += v4[(size_t)(rowbase + r) * 256 + tid];
        ((floatx4*)part1)[(size_t)(b * 128 + sp) * 256 + tid] = acc;
    } else fill_at(out, ATTN_BASE4 + 0 * 8388608LL + (long long)(blk - 256) * 4096);
}
__global__ void fb_mv1_fill(const float* __restrict__ part1, const float* __restrict__ Wv,
                            float* __restrict__ t1p, float* __restrict__ out) {
    int blk = blockIdx.x;
    if (blk < 64) {
        __shared__ float red[256]; __shared__ float vb[32];
        int t = threadIdx.x, b = blk >> 5, ks = blk & 31, k0 = ks * 32;
        int kl = t >> 3, seg = t & 7;
        float s = 0.f;
        #pragma unroll
        for (int i = 0; i < 16; ++i)
            s += part1[(size_t)(b * 128 + seg * 16 + i) * 1024 + k0 + kl];
        red[t] = s; __syncthreads();
        if (t < 32) {
            float v = 0.f;
            #pragma unroll
            for (int j = 0; j < 8; ++j) v += red[t * 8 + j];
            vb[t] = v * (1.0f / 2048.0f);
        }
        __syncthreads();
        const floatx4* W4 = (const floatx4*)Wv;
        floatx4 acc = (floatx4)0.0f;
        #pragma unroll 8
        for (int kk = 0; kk < 32; ++kk) acc += vb[kk] * W4[(size_t)(k0 + kk) * 256 + t];
        ((floatx4*)t1p)[(size_t)(b * 32 + ks) * 256 + t] = acc;
    } else fill_at(out, ATTN_BASE4 + 1 * 8388608LL + (long long)(blk - 64) * 4096);
}
__global__ void fb_mv2_fill(const float* __restrict__ t1p, const float* __restrict__ bv,
                            const float* __restrict__ Wo,
                            float* __restrict__ t2p, float* __restrict__ out) {
    int blk = blockIdx.x;
    if (blk < 64) {
        __shared__ float red[256]; __shared__ float vb2[32];
        int t = threadIdx.x, b = blk >> 5, ks = blk & 31, k0 = ks * 32;
        int kl = t >> 3, seg = t & 7;
        float s = 0.f;
        #pragma unroll
        for (int i = 0; i < 4; ++i)
            s += t1p[(size_t)(b * 32 + seg * 4 + i) * 1024 + k0 + kl];
        red[t] = s; __syncthreads();
        if (t < 32) {
            float v = bv[k0 + t];
            #pragma unroll
            for (int j = 0; j < 8; ++j) v += red[t * 8 + j];
            vb2[t] = v;
        }
        __syncthreads();
        const floatx4* W4 = (const floatx4*)Wo;
        floatx4 acc = (floatx4)0.0f;
        #pragma unroll 8
        for (int kk = 0; kk < 32; ++kk) acc += vb2[kk] * W4[(size_t)(k0 + kk) * 256 + t];
        ((floatx4*)t2p)[(size_t)(b * 32 + ks) * 256 + t] = acc;
    } else fill_at(out, ATTN_BASE4 + 2 * 8388608LL + (long long)(blk - 64) * 4096);
}
__global__ void fb_bcast_fill(const float* __restrict__ t2p, const float* __restrict__ bo,
                              float* __restrict__ out) {
    int blk = blockIdx.x;
    if (blk < 64) {
        __shared__ __align__(16) float orow[1024];
        int t = threadIdx.x, b = blk >> 5, rg = blk & 31;
        #pragma unroll
        for (int cc = 0; cc < 4; ++cc) {
            int col = cc * 256 + t;
            float s = bo[col];
            for (int sp = 0; sp < 32; ++sp)
                s += t2p[(size_t)(b * 32 + sp) * 1024 + col];
            orow[col] = s;
        }
        __syncthreads();
        floatx4 w = ((const floatx4*)orow)[t];
        floatx4* o4 = (floatx4*)out;
        size_t rowbase = ((size_t)b * 2048 + rg * 64) * 256;
        #pragma unroll 4
        for (int r = 0; r < 64; ++r)
            __builtin_nontemporal_store(w, &o4[rowbase + (size_t)r * 256 + t]);
    } else fill_at(out, ATTN_BASE4 + 3 * 8388608LL + (long long)(blk - 64) * 4096);
}

extern "C" void kernel_launch(void* const* d_in, const int* in_sizes, int n_in,
                              void* d_out, int out_size, void* d_ws, size_t ws_size,
                              hipStream_t stream) {
    // inputs: query(0) key(1) value(2) Wq(3) bq(4) Wk(5) bk(6) Wv(7) bv(8) Wo(9) bo(10)
    const float* value = (const float*)d_in[2];
    const float* Wv    = (const float*)d_in[7];
    const float* bv    = (const float*)d_in[8];
    const float* Wo    = (const float*)d_in[9];
    const float* bo    = (const float*)d_in[10];
    float* out = (float*)d_out;
    float* ws  = (float*)d_ws;

    const size_t need = (size_t)(262144 + 1025 * 1024 + 256) * 4;  // ~5.3 MB
    if (ws_size >= need) {
        float* part1 = ws;              // 262144 floats (1 MB)
        float* wc    = ws + 262144;     // 1025*1024 floats (4.1 MB): Wv@Wo + bias row
        k1_colsum_gemm_fill<<<256 + 272 + K1_FILLB, 256, 0, stream>>>(
            value, Wv, bv, Wo, bo, part1, wc, out);
        k2_outrow_bcast_fill<<<64 + K2_FILLB, 256, 0, stream>>>(part1, wc, out);
    } else {
        float* part1 = ws;              // 1 MB
        float* t1p   = ws + 262144;     // 256 KB
        float* t2p   = t1p + 65536;     // 256 KB
        fb_colsum_fill<<<256 + 2048, 256, 0, stream>>>(value, part1, out);
        fb_mv1_fill   <<< 64 + 2048, 256, 0, stream>>>(part1, Wv, t1p, out);
        fb_mv2_fill   <<< 64 + 2048, 256, 0, stream>>>(t1p, bv, Wo, t2p, out);
        fb_bcast_fill <<< 64 + 2048, 256, 0, stream>>>(t2p, bo, out);
    }
}

// Round 5
// 193.858 us; speedup vs baseline: 1.9074x; 1.9074x over previous
//
#include <hip/hip_runtime.h>

// B=2, S=2048, E=1024, H=16.  Output tuple:
//   out  [B,S,E]   =   4,194,304 f32 (rows identical per batch)
//   attn [B,H,S,S] = 134,217,728 f32 (constant 1/2048)
// 553.6 MB of writes -> HBM-write-BW bound; floor ~88 us incl. 42 MB reads.
//
// Depth-2 structure (R4 post-mortem: NO low-occupancy GEMM on the chain):
//  K1: 256 colsum blocks (value -> part1 partials)           || fill chunk A
//  K2: 64 chain blocks, each REDUNDANTLY: vbar=reduce(part1),
//      z=vbar@Wv+bv, outrow=z@Wo+bo (all L2-resident, coalesced 1KB/wave),
//      then broadcast outrow to its own 64 rows of out       || fill chunk B
// All reductions fixed-order -> deterministic across replays.

typedef float floatx4 __attribute__((ext_vector_type(4)));

#define ATTN_BASE4 1048576LL          // B*S*E/4
#define K1_FILLB   4031               // fill blocks in K1
#define K2_FILLB   4161               // fill blocks in K2  (sum = 8192 = attn/4096)

__device__ __forceinline__ void fill_at(float* __restrict__ out, long long f4base) {
    floatx4* o4 = (floatx4*)out;
    const floatx4 av = (floatx4)(1.0f / 2048.0f);   // exact softmax of const scores
    long long base = f4base + threadIdx.x;
    #pragma unroll
    for (int it = 0; it < 16; ++it)
        __builtin_nontemporal_store(av, &o4[base + it * 256]);
}

// ---------------------------------------------------------------------------
// K1: blocks 0..255 -> partial column sums of value (128 splits x 16 rows per
// batch); rest -> fill attn chunk A.
__global__ void __launch_bounds__(256)
k1_colsum_fill(const float* __restrict__ value,
               float* __restrict__ part1,
               float* __restrict__ out) {
    int blk = blockIdx.x, t = threadIdx.x;
    if (blk < 256) {
        int b = blk >> 7, sp = blk & 127;
        const floatx4* v4 = (const floatx4*)value;
        floatx4 acc = (floatx4)0.0f;
        int rowbase = b * 2048 + sp * 16;
        #pragma unroll
        for (int r = 0; r < 16; ++r)
            acc += v4[(size_t)(rowbase + r) * 256 + t];
        ((floatx4*)part1)[(size_t)(b * 128 + sp) * 256 + t] = acc;
    } else {
        fill_at(out, ATTN_BASE4 + (long long)(blk - 256) * 4096);
    }
}

// ---------------------------------------------------------------------------
// K2: blocks 0..63 -> full redundant chain + broadcast of 64 rows each
// (b = blk>>5, row-group = blk&31); rest -> fill attn chunk B.
__global__ void __launch_bounds__(256)
k2_chain_fill(const float* __restrict__ part1,
              const float* __restrict__ Wv, const float* __restrict__ bv,
              const float* __restrict__ Wo, const float* __restrict__ bo,
              float* __restrict__ out) {
    int blk = blockIdx.x, t = threadIdx.x;
    if (blk < 64) {
        __shared__ __align__(16) float vbar[1024];
        __shared__ __align__(16) float zsh[1024];
        int b = blk >> 5, rg = blk & 31;

        // vbar = mean_s value  (reduce 128 partials, fixed order, L2/L3-resident)
        const floatx4* p4 = (const floatx4*)part1 + (size_t)b * 128 * 256;
        floatx4 acc = (floatx4)0.0f;
        #pragma unroll 8
        for (int sp = 0; sp < 128; ++sp)
            acc += p4[sp * 256 + t];
        ((floatx4*)vbar)[t] = acc * (1.0f / 2048.0f);
        __syncthreads();

        // z = vbar @ Wv + bv   (thread t owns cols 4t..4t+3; 1KB/wave coalesced)
        const floatx4* Wv4 = (const floatx4*)Wv;
        floatx4 z = ((const floatx4*)bv)[t];
        #pragma unroll 4
        for (int k4 = 0; k4 < 256; ++k4) {
            floatx4 vb = ((const floatx4*)vbar)[k4];
            z += vb.x * Wv4[(size_t)(4 * k4 + 0) * 256 + t];
            z += vb.y * Wv4[(size_t)(4 * k4 + 1) * 256 + t];
            z += vb.z * Wv4[(size_t)(4 * k4 + 2) * 256 + t];
            z += vb.w * Wv4[(size_t)(4 * k4 + 3) * 256 + t];
        }
        ((floatx4*)zsh)[t] = z;
        __syncthreads();

        // outrow = z @ Wo + bo
        const floatx4* Wo4 = (const floatx4*)Wo;
        floatx4 o = ((const floatx4*)bo)[t];
        #pragma unroll 4
        for (int k4 = 0; k4 < 256; ++k4) {
            floatx4 zz = ((const floatx4*)zsh)[k4];
            o += zz.x * Wo4[(size_t)(4 * k4 + 0) * 256 + t];
            o += zz.y * Wo4[(size_t)(4 * k4 + 1) * 256 + t];
            o += zz.z * Wo4[(size_t)(4 * k4 + 2) * 256 + t];
            o += zz.w * Wo4[(size_t)(4 * k4 + 3) * 256 + t];
        }

        // broadcast outrow to rows [b*2048 + rg*64, +64)
        floatx4* o4out = (floatx4*)out;
        size_t rowstart = (size_t)b * 2048 + (size_t)rg * 64;
        #pragma unroll 8
        for (int r = 0; r < 64; ++r)
            __builtin_nontemporal_store(o, &o4out[(rowstart + r) * 256 + t]);
    } else {
        fill_at(out, ATTN_BASE4 + (long long)K1_FILLB * 4096
                     + (long long)(blk - 64) * 4096);
    }
}

extern "C" void kernel_launch(void* const* d_in, const int* in_sizes, int n_in,
                              void* d_out, int out_size, void* d_ws, size_t ws_size,
                              hipStream_t stream) {
    // inputs: query(0) key(1) value(2) Wq(3) bq(4) Wk(5) bk(6) Wv(7) bv(8) Wo(9) bo(10)
    const float* value = (const float*)d_in[2];
    const float* Wv    = (const float*)d_in[7];
    const float* bv    = (const float*)d_in[8];
    const float* Wo    = (const float*)d_in[9];
    const float* bo    = (const float*)d_in[10];
    float* out = (float*)d_out;
    float* part1 = (float*)d_ws;     // 262144 floats (1 MB)

    k1_colsum_fill<<<256 + K1_FILLB, 256, 0, stream>>>(value, part1, out);
    k2_chain_fill <<< 64 + K2_FILLB, 256, 0, stream>>>(part1, Wv, bv, Wo, bo, out);
}

// Round 6
// 114.097 us; speedup vs baseline: 3.2408x; 1.6991x over previous
//
#include <hip/hip_runtime.h>

// B=2, S=2048, E=1024, H=16.  Output tuple:
//   out  [B,S,E]   = 16 MiB f32 (rows identical per batch)
//   attn [B,H,S,S] = 512 MiB f32 (constant 1/2048)
// HBM-write-BW bound; floor ~89 us incl. ~41 MiB reads at 6.7 TB/s.
//
// R4/R5 lesson: every chain block must have a SMALL read footprint
// (<= ~0.5 MiB) or it outlives its kernel's fill and exposes a tail.
// 3-kernel column-split chain:
//  K1: colsum partials (value -> part1)                     || fill 2512 blk
//  K2: 128 blocks: redundant vbar reduce (512 KiB, cached) +
//      16-col slice of z = vbar@Wv+bv (64 KiB Wv slice)     || fill 2960 blk
//  K3: 128 blocks: z (4 KiB) -> 16-col slice of outrow=z@Wo+bo
//      -> broadcast stripe to 2048 rows                     || fill 2720 blk
// All reductions fixed-order -> deterministic.

typedef float floatx4 __attribute__((ext_vector_type(4)));

#define ATTN_BASE4 1048576LL      // B*S*E/4 (float4 units)
#define K1_FILLB   2512
#define K2_FILLB   2960
#define K3_FILLB   2720           // sum = 8192 = 512 MiB / 64 KiB

__device__ __forceinline__ void fill_at(float* __restrict__ out, long long f4base) {
    floatx4* o4 = (floatx4*)out;
    const floatx4 av = (floatx4)(1.0f / 2048.0f);   // exact softmax of const scores
    long long base = f4base + threadIdx.x;
    #pragma unroll
    for (int it = 0; it < 16; ++it)
        __builtin_nontemporal_store(av, &o4[base + it * 256]);
}

// ---------------------------------------------------------------------------
// K1: blocks 0..255 -> partial column sums of value (2 batches x 128 splits
// of 16 rows); rest -> fill.
__global__ void __launch_bounds__(256)
k1_colsum_fill(const float* __restrict__ value,
               float* __restrict__ part1,
               float* __restrict__ out) {
    int blk = blockIdx.x, t = threadIdx.x;
    if (blk < 256) {
        int b = blk >> 7, sp = blk & 127;
        const floatx4* v4 = (const floatx4*)value;
        floatx4 acc = (floatx4)0.0f;
        int rowbase = b * 2048 + sp * 16;
        #pragma unroll
        for (int r = 0; r < 16; ++r)
            acc += v4[(size_t)(rowbase + r) * 256 + t];
        ((floatx4*)part1)[(size_t)(b * 128 + sp) * 256 + t] = acc;
    } else {
        fill_at(out, ATTN_BASE4 + (long long)(blk - 256) * 4096);
    }
}

// ---------------------------------------------------------------------------
// K2: blocks 0..127 -> (b = blk>>6, 16-col group): redundant vbar reduce,
// then z[cols] = vbar @ Wv[:,cols] + bv[cols]; rest -> fill.
__global__ void __launch_bounds__(256)
k2_z_fill(const float* __restrict__ part1,
          const float* __restrict__ Wv, const float* __restrict__ bv,
          float* __restrict__ z,
          float* __restrict__ out) {
    int blk = blockIdx.x, t = threadIdx.x;
    if (blk < 128) {
        __shared__ __align__(16) float vbar[1024];
        __shared__ float red[256];
        int b = blk >> 6, grp = blk & 63, e0 = grp * 16;

        // vbar = mean_s value (reduce 128 partials; 512 KiB, L2/L3-resident)
        const floatx4* p4 = (const floatx4*)part1 + (size_t)b * 128 * 256;
        floatx4 acc = (floatx4)0.0f;
        #pragma unroll 8
        for (int sp = 0; sp < 128; ++sp)
            acc += p4[sp * 256 + t];
        ((floatx4*)vbar)[t] = acc * (1.0f / 2048.0f);
        __syncthreads();

        // z slice: 16 cols x 16 k-segments of 64
        int col = t & 15, seg = t >> 4;
        const float* wcol = Wv + e0 + col;
        float part = 0.f;
        int k0 = seg * 64;
        #pragma unroll 8
        for (int kk = 0; kk < 64; ++kk) {
            int k = k0 + kk;
            part += vbar[k] * wcol[(size_t)k * 1024];
        }
        red[t] = part;
        __syncthreads();
        if (t < 16) {
            float s = bv[e0 + t];
            #pragma unroll
            for (int g = 0; g < 16; ++g) s += red[g * 16 + t];
            z[b * 1024 + e0 + t] = s;
        }
    } else {
        fill_at(out, ATTN_BASE4 + (long long)K1_FILLB * 4096
                     + (long long)(blk - 128) * 4096);
    }
}

// ---------------------------------------------------------------------------
// K3: blocks 0..127 -> (b, 16-col group): outrow[cols] = z@Wo[:,cols]+bo,
// broadcast the 16-col stripe to all 2048 rows; rest -> fill.
__global__ void __launch_bounds__(256)
k3_orow_bcast_fill(const float* __restrict__ z,
                   const float* __restrict__ Wo, const float* __restrict__ bo,
                   float* __restrict__ out) {
    int blk = blockIdx.x, t = threadIdx.x;
    if (blk < 128) {
        __shared__ __align__(16) float zsh[1024];
        __shared__ float red[256];
        __shared__ __align__(16) float orow[16];
        int b = blk >> 6, grp = blk & 63, e0 = grp * 16;

        ((floatx4*)zsh)[t] = ((const floatx4*)z)[b * 256 + t];
        __syncthreads();

        int col = t & 15, seg = t >> 4;
        const float* wcol = Wo + e0 + col;
        float part = 0.f;
        int k0 = seg * 64;
        #pragma unroll 8
        for (int kk = 0; kk < 64; ++kk) {
            int k = k0 + kk;
            part += zsh[k] * wcol[(size_t)k * 1024];
        }
        red[t] = part;
        __syncthreads();
        if (t < 16) {
            float s = bo[e0 + t];
            #pragma unroll
            for (int g = 0; g < 16; ++g) s += red[g * 16 + t];
            orow[t] = s;
        }
        __syncthreads();

        // broadcast: 16 cols = 4 float4; 256 threads = 4 quads x 64 row-lanes
        int q = t & 3, rl = t >> 2;
        floatx4 w = ((const floatx4*)orow)[q];
        floatx4* o4 = (floatx4*)out;
        size_t cbase = (size_t)(e0 >> 2) + q;
        #pragma unroll 4
        for (int r = rl; r < 2048; r += 64)
            __builtin_nontemporal_store(w, &o4[((size_t)b * 2048 + r) * 256 + cbase]);
    } else {
        fill_at(out, ATTN_BASE4 + (long long)(K1_FILLB + K2_FILLB) * 4096
                     + (long long)(blk - 128) * 4096);
    }
}

extern "C" void kernel_launch(void* const* d_in, const int* in_sizes, int n_in,
                              void* d_out, int out_size, void* d_ws, size_t ws_size,
                              hipStream_t stream) {
    // inputs: query(0) key(1) value(2) Wq(3) bq(4) Wk(5) bk(6) Wv(7) bv(8) Wo(9) bo(10)
    const float* value = (const float*)d_in[2];
    const float* Wv    = (const float*)d_in[7];
    const float* bv    = (const float*)d_in[8];
    const float* Wo    = (const float*)d_in[9];
    const float* bo    = (const float*)d_in[10];
    float* out = (float*)d_out;

    float* part1 = (float*)d_ws;        // 262144 floats (1 MiB)
    float* zbuf  = part1 + 262144;      // 2048 floats

    k1_colsum_fill    <<<256 + K1_FILLB, 256, 0, stream>>>(value, part1, out);
    k2_z_fill         <<<128 + K2_FILLB, 256, 0, stream>>>(part1, Wv, bv, zbuf, out);
    k3_orow_bcast_fill<<<128 + K3_FILLB, 256, 0, stream>>>(zbuf, Wo, bo, out);
}